// Round 6
// baseline (221.453 us; speedup 1.0000x reference)
//
#include <hip/hip_runtime.h>

#define NI 6144
#define NJ 6144
#define M_ROWS 1024
#define K_COLS 256
#define ROWS_PER_BLOCK 8
#define EMD_BLOCKS (NI / ROWS_PER_BLOCK)    // 768 EMD blocks (3/CU on 256 CUs)
#define TOTAL_BLOCKS (EMD_BLOCKS + M_ROWS)  // 768 + 1024 = 1792
#define TSTEPS (NJ / 4 / 256)               // 6 float4-chunks per row/thread

// ---------------------------------------------------------------------------
// Single fused kernel:
//   blocks [0, 768):     EMD partials. Loop nest is row-major: each thread
//                        hoists its 6 y_j fragments (48 floats) into
//                        registers ONCE (reused by all 8 rows), then the
//                        block streams its 8 ADJACENT x rows = one contiguous
//                        196 KB region. 768 long sequential streams
//                        device-wide (was 6144 interleaved 4KB-granular
//                        streams + y_j reloads in the hot loop).
//                        Block sum -> one device-scope atomicAdd to out[0].
//   blocks [768, 1792):  simplex projection, one row of f each (unchanged).
// __launch_bounds__(256,4): <=128 VGPR -> 4 blocks/CU.
// ---------------------------------------------------------------------------
__global__ __launch_bounds__(256, 4) void fused_kernel(
    const float* __restrict__ y_i, const float* __restrict__ y_j,
    const float* __restrict__ x, const float* __restrict__ f,
    float* __restrict__ out) {
  __shared__ float s[K_COLS];
  __shared__ float wpre[4];
  const int tid = threadIdx.x;
  const int lane = tid & 63;
  const int wid = tid >> 6;

  if (blockIdx.x < EMD_BLOCKS) {
    // ---- EMD partial: sum_ij x_ij * (|yi0-yj0| + |yi1-yj1|) ----
    const int row0 = blockIdx.x * ROWS_PER_BLOCK;

    // Hoist this thread's y_j fragments into registers (48 VGPRs).
    const float4* yj4 = (const float4*)y_j;  // (y0,y1,y0,y1) = 2 js per float4
    float4 pj[TSTEPS], qj[TSTEPS];
#pragma unroll
    for (int t = 0; t < TSTEPS; ++t) {
      const int idx = tid + t * 256;
      pj[t] = yj4[2 * idx];      // js 4idx, 4idx+1
      qj[t] = yj4[2 * idx + 1];  // js 4idx+2, 4idx+3
    }

    // Four independent accumulator chains for FMA ILP.
    float a0 = 0.0f, a1 = 0.0f, a2 = 0.0f, a3 = 0.0f;
#pragma unroll
    for (int r = 0; r < ROWS_PER_BLOCK; ++r) {
      const float yi0 = y_i[2 * (row0 + r)];      // uniform -> scalar load
      const float yi1 = y_i[2 * (row0 + r) + 1];
      const float4* xr = (const float4*)(x + (size_t)(row0 + r) * NJ);
#pragma unroll
      for (int t = 0; t < TSTEPS; ++t) {          // 24 KB contiguous per row
        const float4 xv = xr[tid + t * 256];      // coalesced 1KB/wave
        a0 += xv.x * (fabsf(yi0 - pj[t].x) + fabsf(yi1 - pj[t].y));
        a1 += xv.y * (fabsf(yi0 - pj[t].z) + fabsf(yi1 - pj[t].w));
        a2 += xv.z * (fabsf(yi0 - qj[t].x) + fabsf(yi1 - qj[t].y));
        a3 += xv.w * (fabsf(yi0 - qj[t].z) + fabsf(yi1 - qj[t].w));
      }
    }
    float acc = (a0 + a1) + (a2 + a3);

    for (int off = 32; off > 0; off >>= 1) acc += __shfl_down(acc, off, 64);
    if (lane == 0) wpre[wid] = acc;
    __syncthreads();
    if (tid == 0) {
      const float bsum = wpre[0] + wpre[1] + wpre[2] + wpre[3];
      atomicAdd(out, 1.25f * bsum);  // device-scope, cross-XCD safe; 1/R
    }
    return;
  }

  // ---- simplex projection of row (blockIdx.x - EMD_BLOCKS) ----
  const int row = blockIdx.x - EMD_BLOCKS;
  const float fv = f[row * K_COLS + tid];

  // Bitonic sort DESCENDING over 256 values held one-per-thread in xs.
  float xs = fv;
#pragma unroll
  for (int k = 2; k <= 64; k <<= 1) {
#pragma unroll
    for (int j = k >> 1; j > 0; j >>= 1) {       // all j < 64: in-wave
      const float pv = __shfl_xor(xs, j, 64);
      const bool up = ((tid & k) == 0);
      const bool lower = ((tid & j) == 0);
      xs = (up == lower) ? fmaxf(xs, pv) : fminf(xs, pv);
    }
  }
  // k = 128: j=64 via LDS, then j<64 via shfl
  {
    s[tid] = xs; __syncthreads();
    const float pv = s[tid ^ 64]; __syncthreads();
    const bool up = ((tid & 128) == 0);
    xs = (up == ((tid & 64) == 0)) ? fmaxf(xs, pv) : fminf(xs, pv);
#pragma unroll
    for (int j = 32; j > 0; j >>= 1) {
      const float pv2 = __shfl_xor(xs, j, 64);
      xs = (up == ((tid & j) == 0)) ? fmaxf(xs, pv2) : fminf(xs, pv2);
    }
  }
  // k = 256 (final full descending merge)
  {
    s[tid] = xs; __syncthreads();
    float pv = s[tid ^ 128]; __syncthreads();
    xs = ((tid & 128) == 0) ? fmaxf(xs, pv) : fminf(xs, pv);
    s[tid] = xs; __syncthreads();
    pv = s[tid ^ 64]; __syncthreads();
    xs = ((tid & 64) == 0) ? fmaxf(xs, pv) : fminf(xs, pv);
#pragma unroll
    for (int j = 32; j > 0; j >>= 1) {
      const float pv2 = __shfl_xor(xs, j, 64);
      xs = ((tid & j) == 0) ? fmaxf(xs, pv2) : fminf(xs, pv2);
    }
  }

  const float u = xs;  // u[tid] = tid-th largest

  // Inclusive prefix sum of u across 256 threads.
  float cs = u;
#pragma unroll
  for (int off = 1; off < 64; off <<= 1) {
    const float t = __shfl_up(cs, off, 64);
    if (lane >= off) cs += t;
  }
  if (lane == 63) wpre[wid] = cs;
  __syncthreads();
  float base = 0.0f;
#pragma unroll
  for (int w = 0; w < 4; ++w)
    if (w < wid) base += wpre[w];
  cs += base;

  const float vt = (cs - 1.0f) / (float)(tid + 1);
  s[tid] = vt;                                   // reuse s as v-buffer
  const int cnt = __syncthreads_count(u > vt);   // rho + 1 (is a barrier)
  const float w = s[cnt - 1];

  out[1 + row * K_COLS + tid] = fmaxf(fv - w, 0.0f);
}

// ---------------------------------------------------------------------------
extern "C" void kernel_launch(void* const* d_in, const int* in_sizes, int n_in,
                              void* d_out, int out_size, void* d_ws,
                              size_t ws_size, hipStream_t stream) {
  const float* y_i = (const float*)d_in[0];
  const float* y_j = (const float*)d_in[1];
  const float* x   = (const float*)d_in[2];
  const float* f   = (const float*)d_in[3];
  float* out = (float*)d_out;

  fused_kernel<<<TOTAL_BLOCKS, 256, 0, stream>>>(y_i, y_j, x, f, out);
}

// Round 8
// 208.958 us; speedup vs baseline: 1.0598x; 1.0598x over previous
//
#include <hip/hip_runtime.h>

#define NI 6144
#define NJ 6144
#define M_ROWS 1024
#define K_COLS 256
#define ROWS_PER_BLOCK 8
#define EMD_BLOCKS (NI / ROWS_PER_BLOCK)    // 768 EMD blocks (3/CU on 256 CUs)
#define TOTAL_BLOCKS (EMD_BLOCKS + M_ROWS)  // 768 + 1024 = 1792

// Native clang vector type: __builtin_nontemporal_load requires an
// ext_vector, not HIP's float4 class type.
typedef float fvec4 __attribute__((ext_vector_type(4)));

// ---------------------------------------------------------------------------
// Single fused kernel (R4 structure, best measured at 219.3us), ONE change:
// x loads are NONTEMPORAL (via ext_vector_type to satisfy the builtin).
// Mechanism: the harness's 576 MiB poison fill leaves L3 full of dirty
// lines; allocating x reads evict ~151 MB of dirty poison -> the kernel
// window pays read + writeback (~300 MB -> ~38us, matching the measured
// budget). nt reads don't allocate -> kernel carries only the mandatory
// 151 MB read (~25us at 6.3 TB/s).
//   blocks [0, 768):     EMD partials, 8 rows each; block sum -> one
//                        device-scope atomicAdd into out[0].
//   blocks [768, 1792):  simplex projection, one row of f each (unchanged).
// ---------------------------------------------------------------------------
__global__ __launch_bounds__(256, 4) void fused_kernel(
    const float* __restrict__ y_i, const float* __restrict__ y_j,
    const float* __restrict__ x, const float* __restrict__ f,
    float* __restrict__ out) {
  __shared__ float s[K_COLS];
  __shared__ float wpre[4];
  const int tid = threadIdx.x;
  const int lane = tid & 63;
  const int wid = tid >> 6;

  if (blockIdx.x < EMD_BLOCKS) {
    // ---- EMD partial: sum_ij x_ij * (|yi0-yj0| + |yi1-yj1|) ----
    const int row0 = blockIdx.x * ROWS_PER_BLOCK;
    float yi0[ROWS_PER_BLOCK], yi1[ROWS_PER_BLOCK];
#pragma unroll
    for (int r = 0; r < ROWS_PER_BLOCK; ++r) {
      yi0[r] = y_i[2 * (row0 + r)];
      yi1[r] = y_i[2 * (row0 + r) + 1];
    }

    const float4* yj4 = (const float4*)y_j;  // (y0,y1,y0,y1) = 2 js per float4
    float acc = 0.0f;
#pragma unroll
    for (int t = 0; t < NJ / 4 / 256; ++t) {   // 6 iterations, 4 js each
      const int idx = tid + t * 256;
      const float4 p = yj4[2 * idx];           // js 4idx, 4idx+1 (L2 hit)
      const float4 q = yj4[2 * idx + 1];       // js 4idx+2, 4idx+3
#pragma unroll
      for (int r = 0; r < ROWS_PER_BLOCK; ++r) {
        const fvec4 xv = __builtin_nontemporal_load(
            (const fvec4*)(x + (size_t)(row0 + r) * NJ) + idx);  // nt stream
        acc += xv.x * (fabsf(yi0[r] - p.x) + fabsf(yi1[r] - p.y));
        acc += xv.y * (fabsf(yi0[r] - p.z) + fabsf(yi1[r] - p.w));
        acc += xv.z * (fabsf(yi0[r] - q.x) + fabsf(yi1[r] - q.y));
        acc += xv.w * (fabsf(yi0[r] - q.z) + fabsf(yi1[r] - q.w));
      }
    }

    for (int off = 32; off > 0; off >>= 1) acc += __shfl_down(acc, off, 64);
    if (lane == 0) wpre[wid] = acc;
    __syncthreads();
    if (tid == 0) {
      const float bsum = wpre[0] + wpre[1] + wpre[2] + wpre[3];
      atomicAdd(out, 1.25f * bsum);  // device-scope, cross-XCD safe; 1/R
    }
    return;
  }

  // ---- simplex projection of row (blockIdx.x - EMD_BLOCKS) ----
  const int row = blockIdx.x - EMD_BLOCKS;
  const float fv = f[row * K_COLS + tid];

  // Bitonic sort DESCENDING over 256 values held one-per-thread in xs.
  float xs = fv;
#pragma unroll
  for (int k = 2; k <= 64; k <<= 1) {
#pragma unroll
    for (int j = k >> 1; j > 0; j >>= 1) {       // all j < 64: in-wave
      const float pv = __shfl_xor(xs, j, 64);
      const bool up = ((tid & k) == 0);
      const bool lower = ((tid & j) == 0);
      xs = (up == lower) ? fmaxf(xs, pv) : fminf(xs, pv);
    }
  }
  // k = 128: j=64 via LDS, then j<64 via shfl
  {
    s[tid] = xs; __syncthreads();
    const float pv = s[tid ^ 64]; __syncthreads();
    const bool up = ((tid & 128) == 0);
    xs = (up == ((tid & 64) == 0)) ? fmaxf(xs, pv) : fminf(xs, pv);
#pragma unroll
    for (int j = 32; j > 0; j >>= 1) {
      const float pv2 = __shfl_xor(xs, j, 64);
      xs = (up == ((tid & j) == 0)) ? fmaxf(xs, pv2) : fminf(xs, pv2);
    }
  }
  // k = 256 (final full descending merge)
  {
    s[tid] = xs; __syncthreads();
    float pv = s[tid ^ 128]; __syncthreads();
    xs = ((tid & 128) == 0) ? fmaxf(xs, pv) : fminf(xs, pv);
    s[tid] = xs; __syncthreads();
    pv = s[tid ^ 64]; __syncthreads();
    xs = ((tid & 64) == 0) ? fmaxf(xs, pv) : fminf(xs, pv);
#pragma unroll
    for (int j = 32; j > 0; j >>= 1) {
      const float pv2 = __shfl_xor(xs, j, 64);
      xs = ((tid & j) == 0) ? fmaxf(xs, pv2) : fminf(xs, pv2);
    }
  }

  const float u = xs;  // u[tid] = tid-th largest

  // Inclusive prefix sum of u across 256 threads.
  float cs = u;
#pragma unroll
  for (int off = 1; off < 64; off <<= 1) {
    const float t = __shfl_up(cs, off, 64);
    if (lane >= off) cs += t;
  }
  if (lane == 63) wpre[wid] = cs;
  __syncthreads();
  float base = 0.0f;
#pragma unroll
  for (int w = 0; w < 4; ++w)
    if (w < wid) base += wpre[w];
  cs += base;

  const float vt = (cs - 1.0f) / (float)(tid + 1);
  s[tid] = vt;                                   // reuse s as v-buffer
  const int cnt = __syncthreads_count(u > vt);   // rho + 1 (is a barrier)
  const float w = s[cnt - 1];

  out[1 + row * K_COLS + tid] = fmaxf(fv - w, 0.0f);
}

// ---------------------------------------------------------------------------
extern "C" void kernel_launch(void* const* d_in, const int* in_sizes, int n_in,
                              void* d_out, int out_size, void* d_ws,
                              size_t ws_size, hipStream_t stream) {
  const float* y_i = (const float*)d_in[0];
  const float* y_j = (const float*)d_in[1];
  const float* x   = (const float*)d_in[2];
  const float* f   = (const float*)d_in[3];
  float* out = (float*)d_out;

  fused_kernel<<<TOTAL_BLOCKS, 256, 0, stream>>>(y_i, y_j, x, f, out);
}